// Round 14
// baseline (366.995 us; speedup 1.0000x reference)
//
#include <hip/hip_runtime.h>
#include <math.h>

#define N_NODES 100000
#define N_EDGES 3200000
#define D_IN    256
#define D_OUT   128
#define ALPHA   0.2f

// rank-free row-range bucket sort with FIXED bucket strides (no sizes/scan pass:
// softmax+sum commute, so edges only need GROUPING by row, and buckets can be
// padded -- offs[] absorbs the padding).
#define RPB     128                    // rows per bucket (bucket = row >> 7)
#define NBUK2   782                    // ceil(100000/128)
#define MAXBUK  6144                   // fixed stride: mean 4096 + 32 sigma
#define B2TILE  5120                   // edges per bucket2 block (625 blocks, 61% occ)
#define B2PT    (B2TILE / 512)         // 10 edges per thread (register stash)

typedef short bf8_t  __attribute__((ext_vector_type(8)));   // 8 bf16 (MFMA A/B frag)
typedef float f4_t   __attribute__((ext_vector_type(4)));   // 4 f32  (MFMA C/D frag)

// round-to-nearest-even f32 -> bf16
__device__ __forceinline__ unsigned int f2bf(float x) {
    unsigned int u = __float_as_uint(x);
    return (u + 0x7fffu + ((u >> 16) & 1u)) >> 16;
}
__device__ __forceinline__ unsigned int packbf(float lo, float hi) {
    return f2bf(lo) | (f2bf(hi) << 16);
}
__device__ __forceinline__ float bflo(unsigned int v) { return __uint_as_float(v << 16); }
__device__ __forceinline__ float bfhi(unsigned int v) { return __uint_as_float(v & 0xffff0000u); }

// ---------- WTs: W -> bf16 fragment order; also init bucket cursors ----------
__global__ void wt_kernel(const float* __restrict__ W, short* __restrict__ WTs,
                          unsigned int* __restrict__ cursor) {
    int o = blockIdx.x * 256 + threadIdx.x;   // 32768
    if (o < NBUK2) cursor[o * 16] = (unsigned int)o * MAXBUK;   // padded lines
    int j    = o & 7;
    int lane = (o >> 3) & 63;
    int nt   = (o >> 9) & 7;
    int kc   = o >> 12;
    int n = nt * 16 + (lane & 15);
    int k = kc * 32 + (lane >> 4) * 8 + j;
    WTs[o] = (short)f2bf(W[k * 128 + n]);
}

// ---------- GEMM via bf16 MFMA, REGISTER-DIRECT A (no LDS, no barrier) ----------
__global__ __launch_bounds__(256) void gemm_kernel(const float* __restrict__ feat,
                                                   const short* __restrict__ WTs,
                                                   const float* __restrict__ al_w,
                                                   const float* __restrict__ al_b,
                                                   const float* __restrict__ ar_w,
                                                   const float* __restrict__ ar_b,
                                                   unsigned int* __restrict__ seqb,
                                                   float* __restrict__ f1,
                                                   float* __restrict__ f2) {
    const int tid  = threadIdx.x;
    const int w    = tid >> 6;      // wave 0..3 -> rows tb + w*16 ..
    const int lane = tid & 63;
    const int m    = lane & 15;     // A row / B col within tile
    const int q    = lane >> 4;     // quad -> k offset q*8, C rows q*4..q*4+3
    const int tb   = blockIdx.x * 64;

    int gr = tb + w * 16 + m; if (gr >= N_NODES) gr = N_NODES - 1;   // clamp tail
    const float4* fp = (const float4*)(feat + (size_t)gr * 256) + q * 2;

    // ---- A-fragments: 8 x (two float4 loads + pack to bf16x8) = 32 VGPR ----
    bf8_t a[8];
#pragma unroll
    for (int kc = 0; kc < 8; kc++) {
        float4 v0 = fp[kc * 8];          // feat[gr][kc*32 + q*8 + 0..3]
        float4 v1 = fp[kc * 8 + 1];      // feat[gr][kc*32 + q*8 + 4..7]
        uint4 u = make_uint4(packbf(v0.x, v0.y), packbf(v0.z, v0.w),
                             packbf(v1.x, v1.y), packbf(v1.z, v1.w));
        a[kc] = *(const bf8_t*)&u;
    }

    const short* bb = WTs + (size_t)lane * 8;   // + (kc*8+nt)*512 shorts

    f4_t acc[8];
#pragma unroll
    for (int nt = 0; nt < 8; nt++) acc[nt] = (f4_t)(0.f);

#pragma unroll
    for (int kc = 0; kc < 8; kc++) {
#pragma unroll
        for (int nt = 0; nt < 8; nt++) {
            bf8_t b = *(const bf8_t*)(bb + (kc * 8 + nt) * 512);
            acc[nt] = __builtin_amdgcn_mfma_f32_16x16x32_bf16(a[kc], b, acc[nt], 0, 0, 0);
        }
    }

    // ---- epilogue 1: seqb packed bf16x2 (pair adjacent cols via shfl_xor(1)) ----
    const int node_base = tb + w * 16 + q * 4;
#pragma unroll
    for (int nt = 0; nt < 8; nt++) {
#pragma unroll
        for (int j = 0; j < 4; j++) {
            float own   = acc[nt][j];
            float other = __shfl_xor(own, 1);
            int node = node_base + j;
            if (!(lane & 1) && node < N_NODES)
                seqb[(size_t)node * 64 + nt * 8 + (m >> 1)] = packbf(own, other);
        }
    }

    // ---- epilogue 2: f1/f2 = seq . al_w / ar_w (reduce over cols = lanes m) ----
    float p1[4] = {0.f, 0.f, 0.f, 0.f}, p2[4] = {0.f, 0.f, 0.f, 0.f};
#pragma unroll
    for (int nt = 0; nt < 8; nt++) {
        float av = al_w[nt * 16 + m];
        float rv = ar_w[nt * 16 + m];
#pragma unroll
        for (int j = 0; j < 4; j++) {
            p1[j] += acc[nt][j] * av;
            p2[j] += acc[nt][j] * rv;
        }
    }
#pragma unroll
    for (int j = 0; j < 4; j++) {
#pragma unroll
        for (int mk = 1; mk < 16; mk <<= 1) {
            p1[j] += __shfl_xor(p1[j], mk);
            p2[j] += __shfl_xor(p2[j], mk);
        }
    }
    if (m == 0) {
        float alb = al_b[0], arb = ar_b[0];
#pragma unroll
        for (int j = 0; j < 4; j++) {
            int node = node_base + j;
            if (node < N_NODES) {
                f1[node] = p1[j] + alb;
                f2[node] = p2[j] + arb;
            }
        }
    }
}

// ---------- bucket2: row-range bucket of (rlocal,col), FIXED bases ----------
// bucket = r>>7 (bit op), record = (r&127)<<17 | col. Streaming reads, 10-deep
// ILP, 625 blocks = 5000 waves (61% occupancy -- R10/R13 lesson: 250 blocks
// capped the machine at 24%). No per-block metadata -> tile shrink is safe
// (R11's regression came from re-fetched per-chunk metadata, absent here).
__global__ __launch_bounds__(512) void bucket2_kernel(const int* __restrict__ row,
                                                      const int* __restrict__ col,
                                                      unsigned int* __restrict__ cursor,
                                                      unsigned int* __restrict__ records) {
    __shared__ unsigned int hcnt[NBUK2];   // 3.1 KB: counts -> running cursors
    const int tid = threadIdx.x;
    const int base = blockIdx.x * B2TILE;
    for (int i = tid; i < NBUK2; i += 512) hcnt[i] = 0u;
    __syncthreads();

    unsigned int rec[B2PT], bk[B2PT];      // 20 VGPRs, static indices only
#pragma unroll
    for (int it = 0; it < B2PT; it++) {
        int e = base + it * 512 + tid;
        unsigned int r = (unsigned int)row[e];
        bk[it]  = r >> 7;
        rec[it] = ((r & 127u) << 17) | (unsigned int)col[e];
        atomicAdd(&hcnt[bk[it]], 1u);
    }
    __syncthreads();
    for (int i = tid; i < NBUK2; i += 512) {
        unsigned int c = hcnt[i];
        if (c) hcnt[i] = atomicAdd(&cursor[i * 16], c);   // reserve [pos, pos+c)
    }
    __syncthreads();
#pragma unroll
    for (int it = 0; it < B2PT; it++) {
        unsigned int idx = atomicAdd(&hcnt[bk[it]], 1u);
        records[idx] = rec[it];
    }
}

// ---------- csr: per-bucket group-by-row in LDS + coalesced write + offs/cnt ----------
// 512 threads (6256 waves, 76% occupancy; was 3128/38%). Block b: nrec =
// cursor[b] - b*MAXBUK. Read records contiguously, 128-bin histogram + scan,
// scatter cols into LDS window grouped by row, stream window to sorted_c.
__global__ __launch_bounds__(512) void csr_kernel(const unsigned int* __restrict__ records,
                                                  const unsigned int* __restrict__ cursor,
                                                  int* __restrict__ sorted_c,
                                                  unsigned int* __restrict__ offs,
                                                  unsigned int* __restrict__ cnt) {
    __shared__ unsigned int h[RPB], sc[RPB], cur[RPB];
    __shared__ int win[MAXBUK];   // 24 KB
    const int tid = threadIdx.x;
    const int b   = blockIdx.x;
    const unsigned int base = (unsigned int)b * MAXBUK;
    const int nrec = (int)(cursor[b * 16] - base);

    if (tid < RPB) h[tid] = 0u;
    __syncthreads();
    for (int i = tid; i < nrec; i += 512)
        atomicAdd(&h[records[base + i] >> 17], 1u);
    __syncthreads();
    if (tid < RPB) sc[tid] = h[tid];
    __syncthreads();
    for (int d = 1; d < RPB; d <<= 1) {
        unsigned int x = (tid < RPB && tid >= d) ? sc[tid - d] : 0u;
        __syncthreads();
        if (tid < RPB) sc[tid] += x;
        __syncthreads();
    }
    if (tid < RPB) cur[tid] = sc[tid] - h[tid];   // exclusive local offset
    __syncthreads();
    for (int i = tid; i < nrec; i += 512) {
        unsigned int rec = records[base + i];
        unsigned int idx = atomicAdd(&cur[rec >> 17], 1u);
        win[idx] = (int)(rec & 0x1FFFFu);
    }
    __syncthreads();
    for (int i = tid; i < nrec; i += 512)
        sorted_c[base + i] = win[i];
    if (tid < RPB) {
        int r = b * RPB + tid;
        if (r < N_NODES) {
            offs[r] = base + (sc[tid] - h[tid]);
            cnt[r]  = h[tid];
        }
    }
}

// ---------- row aggregate (single kernel, one wave per row) ----------
__global__ __launch_bounds__(256) void row_kernel(const uint4* __restrict__ seqb4,
                                                  const int* __restrict__ sorted_c,
                                                  const unsigned int* __restrict__ offs,
                                                  const unsigned int* __restrict__ cnt,
                                                  const float* __restrict__ f1,
                                                  const float* __restrict__ f2,
                                                  const float* __restrict__ bias,
                                                  float* __restrict__ out) {
    int wid  = (blockIdx.x * 256 + threadIdx.x) >> 6;
    int lane = threadIdx.x & 63;
    int g    = lane >> 4;        // edge group 0..3
    int j4   = lane & 15;        // uint4 index within row: cols 8*j4 .. 8*j4+7
    if (wid >= N_NODES) return;
    unsigned int start = offs[wid];
    unsigned int deg   = cnt[wid];
    const int* sc = sorted_c + start;
    float f1r = f1[wid];

    float a0 = 0.f, a1 = 0.f, a2 = 0.f, a3 = 0.f;
    float a4 = 0.f, a5 = 0.f, a6 = 0.f, a7 = 0.f, ss = 0.f;

    unsigned int k = 0;
    for (; k + 16 <= deg; k += 16) {         // 16 edges: group g handles k+g+4i
        int c0 = sc[k + g];
        int c1 = sc[k + 4 + g];
        int c2 = sc[k + 8 + g];
        int c3 = sc[k + 12 + g];
        uint4 v0 = seqb4[(unsigned)c0 * 16u + j4];
        uint4 v1 = seqb4[(unsigned)c1 * 16u + j4];
        uint4 v2 = seqb4[(unsigned)c2 * 16u + j4];
        uint4 v3 = seqb4[(unsigned)c3 * 16u + j4];
        float t0 = f1r + f2[c0], t1 = f1r + f2[c1];
        float t2 = f1r + f2[c2], t3 = f1r + f2[c3];
        float w0 = __expf(fmaxf(t0, ALPHA * t0));
        float w1 = __expf(fmaxf(t1, ALPHA * t1));
        float w2 = __expf(fmaxf(t2, ALPHA * t2));
        float w3 = __expf(fmaxf(t3, ALPHA * t3));
        ss += (w0 + w1) + (w2 + w3);
        a0 += w0 * bflo(v0.x); a1 += w0 * bfhi(v0.x);
        a2 += w0 * bflo(v0.y); a3 += w0 * bfhi(v0.y);
        a4 += w0 * bflo(v0.z); a5 += w0 * bfhi(v0.z);
        a6 += w0 * bflo(v0.w); a7 += w0 * bfhi(v0.w);
        a0 += w1 * bflo(v1.x); a1 += w1 * bfhi(v1.x);
        a2 += w1 * bflo(v1.y); a3 += w1 * bfhi(v1.y);
        a4 += w1 * bflo(v1.z); a5 += w1 * bfhi(v1.z);
        a6 += w1 * bflo(v1.w); a7 += w1 * bfhi(v1.w);
        a0 += w2 * bflo(v2.x); a1 += w2 * bfhi(v2.x);
        a2 += w2 * bflo(v2.y); a3 += w2 * bfhi(v2.y);
        a4 += w2 * bflo(v2.z); a5 += w2 * bfhi(v2.z);
        a6 += w2 * bflo(v2.w); a7 += w2 * bfhi(v2.w);
        a0 += w3 * bflo(v3.x); a1 += w3 * bfhi(v3.x);
        a2 += w3 * bflo(v3.y); a3 += w3 * bfhi(v3.y);
        a4 += w3 * bflo(v3.z); a5 += w3 * bfhi(v3.z);
        a6 += w3 * bflo(v3.w); a7 += w3 * bfhi(v3.w);
    }
    for (; k + 8 <= deg; k += 8) {
        int ca = sc[k + g];
        int cb = sc[k + 4 + g];
        uint4 va = seqb4[(unsigned)ca * 16u + j4];
        uint4 vb = seqb4[(unsigned)cb * 16u + j4];
        float ta = f1r + f2[ca];
        float tb = f1r + f2[cb];
        float wa = __expf(fmaxf(ta, ALPHA * ta));
        float wb = __expf(fmaxf(tb, ALPHA * tb));
        ss += wa + wb;
        a0 += wa * bflo(va.x); a1 += wa * bfhi(va.x);
        a2 += wa * bflo(va.y); a3 += wa * bfhi(va.y);
        a4 += wa * bflo(va.z); a5 += wa * bfhi(va.z);
        a6 += wa * bflo(va.w); a7 += wa * bfhi(va.w);
        a0 += wb * bflo(vb.x); a1 += wb * bfhi(vb.x);
        a2 += wb * bflo(vb.y); a3 += wb * bfhi(vb.y);
        a4 += wb * bflo(vb.z); a5 += wb * bfhi(vb.z);
        a6 += wb * bflo(vb.w); a7 += wb * bfhi(vb.w);
    }
    for (; k < deg; k += 4) {
        unsigned int ke = k + g;
        int c = sc[ke < deg ? ke : deg - 1];
        uint4 v = seqb4[(unsigned)c * 16u + j4];
        float t = f1r + f2[c];
        float w = __expf(fmaxf(t, ALPHA * t));
        if (ke >= deg) w = 0.f;
        ss += w;
        a0 += w * bflo(v.x); a1 += w * bfhi(v.x);
        a2 += w * bflo(v.y); a3 += w * bfhi(v.y);
        a4 += w * bflo(v.z); a5 += w * bfhi(v.z);
        a6 += w * bflo(v.w); a7 += w * bfhi(v.w);
    }

    a0 += __shfl_xor(a0, 16); a0 += __shfl_xor(a0, 32);
    a1 += __shfl_xor(a1, 16); a1 += __shfl_xor(a1, 32);
    a2 += __shfl_xor(a2, 16); a2 += __shfl_xor(a2, 32);
    a3 += __shfl_xor(a3, 16); a3 += __shfl_xor(a3, 32);
    a4 += __shfl_xor(a4, 16); a4 += __shfl_xor(a4, 32);
    a5 += __shfl_xor(a5, 16); a5 += __shfl_xor(a5, 32);
    a6 += __shfl_xor(a6, 16); a6 += __shfl_xor(a6, 32);
    a7 += __shfl_xor(a7, 16); a7 += __shfl_xor(a7, 32);
    ss += __shfl_xor(ss, 16); ss += __shfl_xor(ss, 32);

    if (g == 0) {
        float inv = (deg > 0) ? 1.f / ss : 0.f;   // empty row -> bias only
        float4 b0 = ((const float4*)bias)[j4 * 2];
        float4 b1 = ((const float4*)bias)[j4 * 2 + 1];
        float4* orow = (float4*)(out + (size_t)wid * D_OUT);
        orow[j4 * 2]     = make_float4(a0 * inv + b0.x, a1 * inv + b0.y,
                                       a2 * inv + b0.z, a3 * inv + b0.w);
        orow[j4 * 2 + 1] = make_float4(a4 * inv + b1.x, a5 * inv + b1.y,
                                       a6 * inv + b1.z, a7 * inv + b1.w);
    }
}

extern "C" void kernel_launch(void* const* d_in, const int* in_sizes, int n_in,
                              void* d_out, int out_size, void* d_ws, size_t ws_size,
                              hipStream_t stream) {
    const float* feat = (const float*)d_in[0];
    const int*   row  = (const int*)d_in[1];
    const int*   col  = (const int*)d_in[2];
    const float* W    = (const float*)d_in[3];
    const float* al_w = (const float*)d_in[4];
    const float* al_b = (const float*)d_in[5];
    const float* ar_w = (const float*)d_in[6];
    const float* ar_b = (const float*)d_in[7];
    const float* bias = (const float*)d_in[8];
    float* out = (float*)d_out;

    char* ws = (char*)d_ws;
    size_t off = 0;
    auto carve = [&](size_t bytes) -> void* {
        off = (off + 255) & ~(size_t)255;
        void* p = ws + off;
        off += bytes;
        return p;
    };
    unsigned int* seqb     = (unsigned int*)carve((size_t)N_NODES * 64 * 4);  // 25.6 MB
    float*        f1       = (float*)       carve((size_t)N_NODES * 4);
    float*        f2       = (float*)       carve((size_t)N_NODES * 4);
    unsigned int* cnt      = (unsigned int*)carve((size_t)N_NODES * 4);
    unsigned int* offs     = (unsigned int*)carve((size_t)N_NODES * 4);
    short*        WTs      = (short*)       carve((size_t)D_IN * D_OUT * 2);
    unsigned int* cursor   = (unsigned int*)carve((size_t)NBUK2 * 64);        // padded lines
    unsigned int* records  = (unsigned int*)carve((size_t)NBUK2 * MAXBUK * 4); // 19.2 MB
    int*          sorted_c = (int*)         carve((size_t)NBUK2 * MAXBUK * 4); // 19.2 MB
    (void)ws_size; (void)in_sizes; (void)n_in; (void)out_size;

    const int nb_gemm = (N_NODES + 63) / 64;    // 1563 (last block guarded)
    const int nb_b2   = N_EDGES / B2TILE;       // 625 exact
    const int nb_row  = N_NODES / 4;            // 25000 exact (4 waves/block)

    wt_kernel<<<(D_IN * D_OUT) / 256, 256, 0, stream>>>(W, WTs, cursor);
    gemm_kernel<<<nb_gemm, 256, 0, stream>>>(feat, WTs, al_w, al_b, ar_w, ar_b, seqb, f1, f2);
    bucket2_kernel<<<nb_b2, 512, 0, stream>>>(row, col, cursor, records);
    csr_kernel<<<NBUK2, 512, 0, stream>>>(records, cursor, sorted_c, offs, cnt);
    row_kernel<<<nb_row, 256, 0, stream>>>((const uint4*)seqb, sorted_c, offs, cnt, f1, f2, bias, out);
}